// Round 1
// baseline (122.551 us; speedup 1.0000x reference)
//
#include <hip/hip_runtime.h>
#include <hip/hip_bf16.h>

#define BATCH     32768
#define TILE      64
#define NPAIR     64
#define MAXSCHED  576
#define LDS_BYTES 81920

typedef __bf16 bf16x8 __attribute__((ext_vector_type(8)));
typedef float  f32x4  __attribute__((ext_vector_type(4)));
static_assert(sizeof(bf16x8) == 16, "bf16x8 must be 16B");

// ---- workspace byte offsets ----
#define WS_CNT      0
#define WS_CURSOR   256
#define WS_NSCHED   512
#define WS_BASE     1024
#define WS_SCHED    2048
#define WS_PAIR     8192
#define WS_ROWLIST  (WS_PAIR + BATCH*4)
#define WS_WT00     (WS_ROWLIST + BATCH*4)
#define WS_WT01     (WS_WT00 + 131072*2)
#define WS_WT1P     (WS_WT01 + 262144*2)
#define WS_WT1A     (WS_WT1P + 131072*2)
#define WS_WT1O     (WS_WT1A + 393216*2)

__device__ __forceinline__ unsigned short f2bf(float x) {
  __bf16 h = (__bf16)x;
  return __builtin_bit_cast(unsigned short, h);
}

__global__ __launch_bounds__(64) void k_init(int* cnt) {
  cnt[threadIdx.x] = 0;
}

__global__ __launch_bounds__(256) void k_route(const float* __restrict__ inp,
                                               int* __restrict__ pairArr,
                                               int* __restrict__ cnt) {
  __shared__ int h[NPAIR];
  int t = threadIdx.x;
  if (t < NPAIR) h[t] = 0;
  __syncthreads();
  int r = blockIdx.x * 256 + t;
  const float* q = inp + (size_t)r * 144 + 128;
  float4 u0 = *(const float4*)(q + 0);
  float4 u1 = *(const float4*)(q + 4);
  float4 v0 = *(const float4*)(q + 8);
  float4 v1 = *(const float4*)(q + 12);
  int a0 = 0;
  if (u0.y > 0.5f) a0 = 1; if (u0.z > 0.5f) a0 = 2; if (u0.w > 0.5f) a0 = 3;
  if (u1.x > 0.5f) a0 = 4; if (u1.y > 0.5f) a0 = 5; if (u1.z > 0.5f) a0 = 6; if (u1.w > 0.5f) a0 = 7;
  int a1 = 0;
  if (v0.y > 0.5f) a1 = 1; if (v0.z > 0.5f) a1 = 2; if (v0.w > 0.5f) a1 = 3;
  if (v1.x > 0.5f) a1 = 4; if (v1.y > 0.5f) a1 = 5; if (v1.z > 0.5f) a1 = 6; if (v1.w > 0.5f) a1 = 7;
  int p = a0 * 8 + a1;
  pairArr[r] = p;
  atomicAdd(&h[p], 1);
  __syncthreads();
  if (t < NPAIR && h[t] > 0) atomicAdd(&cnt[t], h[t]);
}

__global__ __launch_bounds__(64) void k_scan(const int* __restrict__ cnt,
                                             int* __restrict__ base,
                                             int* __restrict__ cursor,
                                             int* __restrict__ sched,
                                             int* __restrict__ nsched) {
  int p = threadIdx.x;  // one wave of 64
  int c = cnt[p];
  int x = c;
  #pragma unroll
  for (int d = 1; d < 64; d <<= 1) { int y = __shfl_up(x, d); if (p >= d) x += y; }
  base[p]   = x - c;
  cursor[p] = x - c;
  int nt = (c + TILE - 1) / TILE;
  int z = nt;
  #pragma unroll
  for (int d = 1; d < 64; d <<= 1) { int y = __shfl_up(z, d); if (p >= d) z += y; }
  int tb = z - nt;
  for (int t2 = 0; t2 < nt; ++t2) sched[tb + t2] = (p << 10) | t2;
  if (p == 63) *nsched = tb + nt;
}

__global__ __launch_bounds__(256) void k_scatter(const int* __restrict__ pairArr,
                                                 int* __restrict__ cursor,
                                                 int* __restrict__ rowlist) {
  int r = blockIdx.x * 256 + threadIdx.x;
  int p = pairArr[r];
  int pos = atomicAdd(&cursor[p], 1);
  rowlist[pos] = r;
}

// Transpose W[m][i][o] fp32 -> Wt[m][o][i] bf16 (64x64 LDS tiles, both sides coalesced)
__global__ __launch_bounds__(256) void k_prep(const float* __restrict__ w00,
                                              const float* __restrict__ w01,
                                              const float* __restrict__ w1p,
                                              const float* __restrict__ w1a,
                                              const float* __restrict__ w1o,
                                              char* __restrict__ ws) {
  __shared__ unsigned short lds[64 * 72];
  int bid = blockIdx.x;
  const float* src; unsigned short* dst; int I, O, lt;
  if (bid < 32)       { src = w00; dst = (unsigned short*)(ws + WS_WT00); I = 64;  O = 256; lt = bid; }
  else if (bid < 96)  { src = w01; dst = (unsigned short*)(ws + WS_WT01); I = 256; O = 128; lt = bid - 32; }
  else if (bid < 128) { src = w1p; dst = (unsigned short*)(ws + WS_WT1P); I = 64;  O = 256; lt = bid - 96; }
  else if (bid < 224) { src = w1a; dst = (unsigned short*)(ws + WS_WT1A); I = 384; O = 128; lt = bid - 128; }
  else                { src = w1o; dst = (unsigned short*)(ws + WS_WT1O); I = 128; O = 32;  lt = bid - 224; }
  int tI = I >> 6;
  int tO = (O + 63) >> 6;
  int m   = lt / (tI * tO);
  int rem = lt % (tI * tO);
  int ib = rem / tO, ob = rem % tO;
  int tx = threadIdx.x & 63, ty = threadIdx.x >> 6;
  const float* s = src + (size_t)m * I * O;
  #pragma unroll 4
  for (int s4 = 0; s4 < 16; ++s4) {
    int li = s4 * 4 + ty;
    int o  = ob * 64 + tx;
    float v = (o < O) ? s[(size_t)(ib * 64 + li) * O + o] : 0.f;
    lds[li * 72 + tx] = f2bf(v);
  }
  __syncthreads();
  unsigned short* d = dst + (size_t)m * O * I;
  #pragma unroll 4
  for (int s4 = 0; s4 < 16; ++s4) {
    int lo = s4 * 4 + ty;
    int o  = ob * 64 + lo;
    if (o < O) d[(size_t)o * I + ib * 64 + tx] = lds[tx * 72 + lo];
  }
}

// Fused 5-layer routed MLP: one block = 64 rows sharing (a0,a1); 8 waves.
// LDS: H1 64x256 bf16 (stride 512B) @0 (G2 64x128 stride 256B aliases it),
//      CAT 64x384 bf16 (stride 768B) @32768.  XOR swizzle: byte ^= (row&7)<<4.
__global__ __launch_bounds__(512, 4) void k_fused(
    const float* __restrict__ inp,
    const float* __restrict__ b00, const float* __restrict__ b01,
    const float* __restrict__ b1p, const float* __restrict__ b1a,
    const float* __restrict__ b1o,
    char* __restrict__ ws, float* __restrict__ out)
{
  extern __shared__ char smem[];
  unsigned short* H1  = (unsigned short*)smem;
  unsigned short* CAT = (unsigned short*)(smem + 32768);

  int sid = blockIdx.x;
  int ns = *(const int*)(ws + WS_NSCHED);
  if (sid >= ns) return;
  int ent = ((const int*)(ws + WS_SCHED))[sid];
  int p = ent >> 10, t = ent & 1023;
  int e0 = p >> 3, e1 = p & 7;
  int c  = ((const int*)(ws + WS_CNT))[p];
  int rb = ((const int*)(ws + WS_BASE))[p] + t * TILE;
  int nr = min(TILE, c - t * TILE);
  const int* rl = (const int*)(ws + WS_ROWLIST) + rb;

  const unsigned short* wt00 = (const unsigned short*)(ws + WS_WT00);
  const unsigned short* wt01 = (const unsigned short*)(ws + WS_WT01);
  const unsigned short* wt1p = (const unsigned short*)(ws + WS_WT1P);
  const unsigned short* wt1a = (const unsigned short*)(ws + WS_WT1A);
  const unsigned short* wt1o = (const unsigned short*)(ws + WS_WT1O);

  int lane = threadIdx.x & 63;
  int w    = threadIdx.x >> 6;   // wave 0..7
  int ln   = lane & 15;
  int lq   = lane >> 4;          // 0..3
  int kcol = lq * 8;

  int rowA[4];
  #pragma unroll
  for (int mt = 0; mt < 4; ++mt) {
    int rloc = mt * 16 + ln;
    rowA[mt] = (rloc < nr) ? rl[rloc] : -1;
  }

  const f32x4 z4 = {0.f, 0.f, 0.f, 0.f};

  // ===== L00: feat0 (cols 0..63) @ W00[e0] -> H1 (256), relu =====
  {
    bf16x8 ax[4][2];
    #pragma unroll
    for (int mt = 0; mt < 4; ++mt) {
      #pragma unroll
      for (int kc = 0; kc < 2; ++kc) {
        bf16x8 a;
        int rg = rowA[mt];
        if (rg >= 0) {
          const float* q = inp + (size_t)rg * 144 + kc * 32 + kcol;
          float4 u = *(const float4*)(q);
          float4 v = *(const float4*)(q + 4);
          a[0] = (__bf16)u.x; a[1] = (__bf16)u.y; a[2] = (__bf16)u.z; a[3] = (__bf16)u.w;
          a[4] = (__bf16)v.x; a[5] = (__bf16)v.y; a[6] = (__bf16)v.z; a[7] = (__bf16)v.w;
        } else {
          #pragma unroll
          for (int j = 0; j < 8; ++j) a[j] = (__bf16)0.f;
        }
        ax[mt][kc] = a;
      }
    }
    #pragma unroll
    for (int nt = 0; nt < 2; ++nt) {
      int n = w * 32 + nt * 16 + ln;  // 0..255
      f32x4 acc[4] = {z4, z4, z4, z4};
      #pragma unroll
      for (int kc = 0; kc < 2; ++kc) {
        bf16x8 bfr = *(const bf16x8*)(wt00 + ((size_t)(e0 * 256 + n) * 64 + kc * 32 + kcol));
        #pragma unroll
        for (int mt = 0; mt < 4; ++mt)
          acc[mt] = __builtin_amdgcn_mfma_f32_16x16x32_bf16(ax[mt][kc], bfr, acc[mt], 0, 0, 0);
      }
      float bias = b00[e0 * 256 + n];
      #pragma unroll
      for (int mt = 0; mt < 4; ++mt) {
        #pragma unroll
        for (int r = 0; r < 4; ++r) {
          int row = mt * 16 + lq * 4 + r;
          float v = fmaxf(acc[mt][r] + bias, 0.f);
          H1[(row * 512 + ((n << 1) ^ ((row & 7) << 4))) >> 1] = f2bf(v);
        }
      }
    }
  }
  __syncthreads();

  // ===== L01: H1 @ W01[e0] -> CAT[:,0:128), relu =====
  {
    int n = w * 16 + ln;  // 0..127
    f32x4 acc[4] = {z4, z4, z4, z4};
    #pragma unroll
    for (int kc = 0; kc < 8; ++kc) {
      bf16x8 bfr = *(const bf16x8*)(wt01 + ((size_t)(e0 * 128 + n) * 256 + kc * 32 + kcol));
      #pragma unroll
      for (int mt = 0; mt < 4; ++mt) {
        int row = mt * 16 + ln;
        bf16x8 afr = *(const bf16x8*)&H1[(row * 512 + (((kc * 32 + kcol) << 1) ^ ((row & 7) << 4))) >> 1];
        acc[mt] = __builtin_amdgcn_mfma_f32_16x16x32_bf16(afr, bfr, acc[mt], 0, 0, 0);
      }
    }
    float bias = b01[e0 * 128 + n];
    #pragma unroll
    for (int mt = 0; mt < 4; ++mt) {
      #pragma unroll
      for (int r = 0; r < 4; ++r) {
        int row = mt * 16 + lq * 4 + r;
        float v = fmaxf(acc[mt][r] + bias, 0.f);
        CAT[(row * 768 + ((n << 1) ^ ((row & 7) << 4))) >> 1] = f2bf(v);
      }
    }
  }

  // ===== L1p: feat1 (cols 64..127) @ W1p[e1] -> CAT[:,128:384), relu (no barrier needed) =====
  {
    bf16x8 ax[4][2];
    #pragma unroll
    for (int mt = 0; mt < 4; ++mt) {
      #pragma unroll
      for (int kc = 0; kc < 2; ++kc) {
        bf16x8 a;
        int rg = rowA[mt];
        if (rg >= 0) {
          const float* q = inp + (size_t)rg * 144 + 64 + kc * 32 + kcol;
          float4 u = *(const float4*)(q);
          float4 v = *(const float4*)(q + 4);
          a[0] = (__bf16)u.x; a[1] = (__bf16)u.y; a[2] = (__bf16)u.z; a[3] = (__bf16)u.w;
          a[4] = (__bf16)v.x; a[5] = (__bf16)v.y; a[6] = (__bf16)v.z; a[7] = (__bf16)v.w;
        } else {
          #pragma unroll
          for (int j = 0; j < 8; ++j) a[j] = (__bf16)0.f;
        }
        ax[mt][kc] = a;
      }
    }
    #pragma unroll
    for (int nt = 0; nt < 2; ++nt) {
      int n = w * 32 + nt * 16 + ln;  // 0..255
      f32x4 acc[4] = {z4, z4, z4, z4};
      #pragma unroll
      for (int kc = 0; kc < 2; ++kc) {
        bf16x8 bfr = *(const bf16x8*)(wt1p + ((size_t)(e1 * 256 + n) * 64 + kc * 32 + kcol));
        #pragma unroll
        for (int mt = 0; mt < 4; ++mt)
          acc[mt] = __builtin_amdgcn_mfma_f32_16x16x32_bf16(ax[mt][kc], bfr, acc[mt], 0, 0, 0);
      }
      float bias = b1p[e1 * 256 + n];
      int colb = (128 + n) << 1;
      #pragma unroll
      for (int mt = 0; mt < 4; ++mt) {
        #pragma unroll
        for (int r = 0; r < 4; ++r) {
          int row = mt * 16 + lq * 4 + r;
          float v = fmaxf(acc[mt][r] + bias, 0.f);
          CAT[(row * 768 + (colb ^ ((row & 7) << 4))) >> 1] = f2bf(v);
        }
      }
    }
  }
  __syncthreads();

  // ===== L1a: CAT (384) @ W1a[e1] -> G2 (128, aliases H1 region), relu =====
  {
    int n = w * 16 + ln;  // 0..127
    f32x4 acc[4] = {z4, z4, z4, z4};
    #pragma unroll
    for (int kc = 0; kc < 12; ++kc) {
      bf16x8 bfr = *(const bf16x8*)(wt1a + ((size_t)(e1 * 128 + n) * 384 + kc * 32 + kcol));
      #pragma unroll
      for (int mt = 0; mt < 4; ++mt) {
        int row = mt * 16 + ln;
        bf16x8 afr = *(const bf16x8*)&CAT[(row * 768 + (((kc * 32 + kcol) << 1) ^ ((row & 7) << 4))) >> 1];
        acc[mt] = __builtin_amdgcn_mfma_f32_16x16x32_bf16(afr, bfr, acc[mt], 0, 0, 0);
      }
    }
    float bias = b1a[e1 * 128 + n];
    #pragma unroll
    for (int mt = 0; mt < 4; ++mt) {
      #pragma unroll
      for (int r = 0; r < 4; ++r) {
        int row = mt * 16 + lq * 4 + r;
        float v = fmaxf(acc[mt][r] + bias, 0.f);
        H1[(row * 256 + ((n << 1) ^ ((row & 7) << 4))) >> 1] = f2bf(v);  // G2, stride 256B
      }
    }
  }
  __syncthreads();

  // ===== L1o: G2 (128) @ W1o[e1] -> out (32), no relu, scatter fp32 =====
  {
    int mt = w >> 1;             // 0..3
    int n  = (w & 1) * 16 + ln;  // 0..31
    f32x4 acc = z4;
    #pragma unroll
    for (int kc = 0; kc < 4; ++kc) {
      bf16x8 bfr = *(const bf16x8*)(wt1o + ((size_t)(e1 * 32 + n) * 128 + kc * 32 + kcol));
      int row = mt * 16 + ln;
      bf16x8 afr = *(const bf16x8*)&H1[(row * 256 + (((kc * 32 + kcol) << 1) ^ ((row & 7) << 4))) >> 1];
      acc = __builtin_amdgcn_mfma_f32_16x16x32_bf16(afr, bfr, acc, 0, 0, 0);
    }
    float bias = b1o[e1 * 32 + n];
    #pragma unroll
    for (int r = 0; r < 4; ++r) {
      int row = mt * 16 + lq * 4 + r;
      if (row < nr) {
        int rg = rl[row];
        out[(size_t)rg * 32 + n] = acc[r] + bias;
      }
    }
  }
}

extern "C" void kernel_launch(void* const* d_in, const int* in_sizes, int n_in,
                              void* d_out, int out_size, void* d_ws, size_t ws_size,
                              hipStream_t stream) {
  const float* inp = (const float*)d_in[0];
  const float* w00 = (const float*)d_in[1];
  const float* b00 = (const float*)d_in[2];
  const float* w01 = (const float*)d_in[3];
  const float* b01 = (const float*)d_in[4];
  const float* w1p = (const float*)d_in[5];
  const float* b1p = (const float*)d_in[6];
  const float* w1a = (const float*)d_in[7];
  const float* b1a = (const float*)d_in[8];
  const float* w1o = (const float*)d_in[9];
  const float* b1o = (const float*)d_in[10];
  char*  ws  = (char*)d_ws;
  float* out = (float*)d_out;

  (void)hipFuncSetAttribute(reinterpret_cast<const void*>(k_fused),
                            hipFuncAttributeMaxDynamicSharedMemorySize, LDS_BYTES);

  k_init<<<1, 64, 0, stream>>>((int*)(ws + WS_CNT));
  k_prep<<<240, 256, 0, stream>>>(w00, w01, w1p, w1a, w1o, ws);
  k_route<<<BATCH / 256, 256, 0, stream>>>(inp, (int*)(ws + WS_PAIR), (int*)(ws + WS_CNT));
  k_scan<<<1, 64, 0, stream>>>((const int*)(ws + WS_CNT), (int*)(ws + WS_BASE),
                               (int*)(ws + WS_CURSOR), (int*)(ws + WS_SCHED),
                               (int*)(ws + WS_NSCHED));
  k_scatter<<<BATCH / 256, 256, 0, stream>>>((const int*)(ws + WS_PAIR),
                                             (int*)(ws + WS_CURSOR),
                                             (int*)(ws + WS_ROWLIST));
  k_fused<<<MAXSCHED, 512, LDS_BYTES, stream>>>(inp, b00, b01, b1p, b1a, b1o, ws, out);
}

// Round 2
// 99.926 us; speedup vs baseline: 1.2264x; 1.2264x over previous
//
#include <hip/hip_runtime.h>
#include <hip/hip_bf16.h>

#define BATCH     32768
#define TILE      32
#define NPAIR     64
#define NBLK      128          /* route/scatter blocks: BATCH/256 */
#define MAXSCHED  1088         /* 64 + BATCH/TILE */

typedef __bf16 bf16x8 __attribute__((ext_vector_type(8)));
typedef float  f32x4  __attribute__((ext_vector_type(4)));
static_assert(sizeof(bf16x8) == 16, "bf16x8 must be 16B");

// ---- workspace byte offsets ----
#define WS_CNT      0
#define WS_BASE     256
#define WS_NSCHED   512
#define WS_SCHED    1024
#define WS_BH       8192
#define WS_OFF      (WS_BH + NBLK*NPAIR*4)
#define WS_PAIR     (WS_OFF + NBLK*NPAIR*4)
#define WS_ROWLIST  (WS_PAIR + BATCH*4)
#define WS_WT00     (WS_ROWLIST + BATCH*4)
#define WS_WT01     (WS_WT00 + 131072*2)
#define WS_WT1P     (WS_WT01 + 262144*2)
#define WS_WT1A     (WS_WT1P + 131072*2)
#define WS_WT1O     (WS_WT1A + 393216*2)

__device__ __forceinline__ unsigned short f2bf(float x) {
  __bf16 h = (__bf16)x;
  return __builtin_bit_cast(unsigned short, h);
}

// Route: per-block histogram only, NO global atomics.
__global__ __launch_bounds__(256) void k_route(const float* __restrict__ inp,
                                               int* __restrict__ pairArr,
                                               int* __restrict__ bh) {
  __shared__ int h[NPAIR];
  int t = threadIdx.x;
  if (t < NPAIR) h[t] = 0;
  __syncthreads();
  int r = blockIdx.x * 256 + t;
  const float* q = inp + (size_t)r * 144 + 128;
  float4 u0 = *(const float4*)(q + 0);
  float4 u1 = *(const float4*)(q + 4);
  float4 v0 = *(const float4*)(q + 8);
  float4 v1 = *(const float4*)(q + 12);
  int a0 = 0;
  if (u0.y > 0.5f) a0 = 1; if (u0.z > 0.5f) a0 = 2; if (u0.w > 0.5f) a0 = 3;
  if (u1.x > 0.5f) a0 = 4; if (u1.y > 0.5f) a0 = 5; if (u1.z > 0.5f) a0 = 6; if (u1.w > 0.5f) a0 = 7;
  int a1 = 0;
  if (v0.y > 0.5f) a1 = 1; if (v0.z > 0.5f) a1 = 2; if (v0.w > 0.5f) a1 = 3;
  if (v1.x > 0.5f) a1 = 4; if (v1.y > 0.5f) a1 = 5; if (v1.z > 0.5f) a1 = 6; if (v1.w > 0.5f) a1 = 7;
  int p = a0 * 8 + a1;
  pairArr[r] = p;
  atomicAdd(&h[p], 1);
  __syncthreads();
  if (t < NPAIR) bh[blockIdx.x * NPAIR + t] = h[t];
}

// Scan: one wave. Global counts, bases, per-(block,pair) offsets, tile schedule.
__global__ __launch_bounds__(64) void k_scan(const int* __restrict__ bh,
                                             int* __restrict__ cnt,
                                             int* __restrict__ base,
                                             int* __restrict__ off,
                                             int* __restrict__ sched,
                                             int* __restrict__ nsched) {
  int p = threadIdx.x;  // 0..63
  int run = 0;
  for (int b = 0; b < NBLK; ++b) { off[b * NPAIR + p] = run; run += bh[b * NPAIR + p]; }
  int c = run;
  cnt[p] = c;
  int x = c;
  #pragma unroll
  for (int d = 1; d < 64; d <<= 1) { int y = __shfl_up(x, d); if (p >= d) x += y; }
  int bs = x - c;
  base[p] = bs;
  for (int b = 0; b < NBLK; ++b) off[b * NPAIR + p] += bs;
  int nt = (c + TILE - 1) / TILE;
  int z = nt;
  #pragma unroll
  for (int d = 1; d < 64; d <<= 1) { int y = __shfl_up(z, d); if (p >= d) z += y; }
  int tb = z - nt;
  for (int t2 = 0; t2 < nt; ++t2) sched[tb + t2] = (p << 16) | t2;
  if (p == 63) *nsched = tb + nt;
}

// Scatter: LDS-local rank + precomputed global offset. NO global atomics.
__global__ __launch_bounds__(256) void k_scatter(const int* __restrict__ pairArr,
                                                 const int* __restrict__ off,
                                                 int* __restrict__ rowlist) {
  __shared__ int h[NPAIR];
  int t = threadIdx.x;
  if (t < NPAIR) h[t] = 0;
  __syncthreads();
  int r = blockIdx.x * 256 + t;
  int p = pairArr[r];
  int rank = atomicAdd(&h[p], 1);
  rowlist[off[blockIdx.x * NPAIR + p] + rank] = r;
}

// Transpose W[m][i][o] fp32 -> Wt[m][o][i] bf16 (64x64 LDS tiles, both sides coalesced)
__global__ __launch_bounds__(256) void k_prep(const float* __restrict__ w00,
                                              const float* __restrict__ w01,
                                              const float* __restrict__ w1p,
                                              const float* __restrict__ w1a,
                                              const float* __restrict__ w1o,
                                              char* __restrict__ ws) {
  __shared__ unsigned short lds[64 * 72];
  int bid = blockIdx.x;
  const float* src; unsigned short* dst; int I, O, lt;
  if (bid < 32)       { src = w00; dst = (unsigned short*)(ws + WS_WT00); I = 64;  O = 256; lt = bid; }
  else if (bid < 96)  { src = w01; dst = (unsigned short*)(ws + WS_WT01); I = 256; O = 128; lt = bid - 32; }
  else if (bid < 128) { src = w1p; dst = (unsigned short*)(ws + WS_WT1P); I = 64;  O = 256; lt = bid - 96; }
  else if (bid < 224) { src = w1a; dst = (unsigned short*)(ws + WS_WT1A); I = 384; O = 128; lt = bid - 128; }
  else                { src = w1o; dst = (unsigned short*)(ws + WS_WT1O); I = 128; O = 32;  lt = bid - 224; }
  int tI = I >> 6;
  int tO = (O + 63) >> 6;
  int m   = lt / (tI * tO);
  int rem = lt % (tI * tO);
  int ib = rem / tO, ob = rem % tO;
  int tx = threadIdx.x & 63, ty = threadIdx.x >> 6;
  const float* s = src + (size_t)m * I * O;
  #pragma unroll 4
  for (int s4 = 0; s4 < 16; ++s4) {
    int li = s4 * 4 + ty;
    int o  = ob * 64 + tx;
    float v = (o < O) ? s[(size_t)(ib * 64 + li) * O + o] : 0.f;
    lds[li * 72 + tx] = f2bf(v);
  }
  __syncthreads();
  unsigned short* d = dst + (size_t)m * O * I;
  #pragma unroll 4
  for (int s4 = 0; s4 < 16; ++s4) {
    int lo = s4 * 4 + ty;
    int o  = ob * 64 + lo;
    if (o < O) d[(size_t)o * I + ib * 64 + tx] = lds[tx * 72 + lo];
  }
}

// Fused 5-layer routed MLP. One block = 32 rows sharing (a0,a1); 4 waves; 32KB LDS.
// Order: L1p -> [bar] -> L1a-partial(g) + L00 -> [bar] -> L01 -> [bar] ->
//        L1a-finish(h) -> [bar] -> L1o.
// LDS: G (32x256, stride 512B) @0; H1 (32x256) @16K;
//      HO (32x128, stride 256B) @0 aliases dead G; G2 (32x128) @8K aliases dead G.
// Swizzle: byte ^= (row&7)<<4 on all tiles.
__global__ __launch_bounds__(256, 5) void k_fused(
    const float* __restrict__ inp,
    const float* __restrict__ b00, const float* __restrict__ b01,
    const float* __restrict__ b1p, const float* __restrict__ b1a,
    const float* __restrict__ b1o,
    const char* __restrict__ ws, float* __restrict__ out)
{
  __shared__ char smem[32768];
  unsigned short* G   = (unsigned short*)smem;
  unsigned short* H1m = (unsigned short*)(smem + 16384);
  unsigned short* HO  = (unsigned short*)smem;
  unsigned short* G2  = (unsigned short*)(smem + 8192);

  int ns = *(const int*)(ws + WS_NSCHED);
  if (blockIdx.x >= ns) return;
  int ent = ((const int*)(ws + WS_SCHED))[blockIdx.x];
  int p = ent >> 16, t = ent & 0xffff;
  int e0 = p >> 3, e1 = p & 7;
  int c  = ((const int*)(ws + WS_CNT))[p];
  int rb = ((const int*)(ws + WS_BASE))[p] + t * TILE;
  int nr = min(TILE, c - t * TILE);
  const int* rl = (const int*)(ws + WS_ROWLIST) + rb;

  const unsigned short* wt00 = (const unsigned short*)(ws + WS_WT00);
  const unsigned short* wt01 = (const unsigned short*)(ws + WS_WT01);
  const unsigned short* wt1p = (const unsigned short*)(ws + WS_WT1P);
  const unsigned short* wt1a = (const unsigned short*)(ws + WS_WT1A);
  const unsigned short* wt1o = (const unsigned short*)(ws + WS_WT1O);

  int lane = threadIdx.x & 63;
  int w    = threadIdx.x >> 6;   // wave 0..3
  int ln   = lane & 15;
  int lq   = lane >> 4;          // 0..3
  int kcol = lq * 8;

  int rowA[2];
  #pragma unroll
  for (int mt = 0; mt < 2; ++mt) {
    int rloc = mt * 16 + ln;
    rowA[mt] = (rloc < nr) ? rl[rloc] : -1;
  }

  // Load both feature halves up-front (16 float4 loads in flight).
  bf16x8 axf[2][2][2];  // [half][mt][kc]
  #pragma unroll
  for (int mt = 0; mt < 2; ++mt) {
    #pragma unroll
    for (int half = 0; half < 2; ++half) {
      #pragma unroll
      for (int kc = 0; kc < 2; ++kc) {
        bf16x8 a;
        int rg = rowA[mt];
        if (rg >= 0) {
          const float* q = inp + (size_t)rg * 144 + half * 64 + kc * 32 + kcol;
          float4 u = *(const float4*)(q);
          float4 v = *(const float4*)(q + 4);
          a[0] = (__bf16)u.x; a[1] = (__bf16)u.y; a[2] = (__bf16)u.z; a[3] = (__bf16)u.w;
          a[4] = (__bf16)v.x; a[5] = (__bf16)v.y; a[6] = (__bf16)v.z; a[7] = (__bf16)v.w;
        } else {
          #pragma unroll
          for (int j = 0; j < 8; ++j) a[j] = (__bf16)0.f;
        }
        axf[half][mt][kc] = a;
      }
    }
  }

  const f32x4 z4 = {0.f, 0.f, 0.f, 0.f};

  // ===== L1p: feat1 @ W1p[e1] -> G (256), relu =====
  #pragma unroll
  for (int nt = 0; nt < 4; ++nt) {
    int n = w * 64 + nt * 16 + ln;  // 0..255
    f32x4 acc[2] = {z4, z4};
    #pragma unroll
    for (int kc = 0; kc < 2; ++kc) {
      bf16x8 bfr = *(const bf16x8*)(wt1p + ((size_t)(e1 * 256 + n) * 64 + kc * 32 + kcol));
      #pragma unroll
      for (int mt = 0; mt < 2; ++mt)
        acc[mt] = __builtin_amdgcn_mfma_f32_16x16x32_bf16(axf[1][mt][kc], bfr, acc[mt], 0, 0, 0);
    }
    float bias = b1p[e1 * 256 + n];
    #pragma unroll
    for (int mt = 0; mt < 2; ++mt) {
      #pragma unroll
      for (int r = 0; r < 4; ++r) {
        int row = mt * 16 + lq * 4 + r;
        float v = fmaxf(acc[mt][r] + bias, 0.f);
        G[(row * 512 + ((n << 1) ^ ((row & 7) << 4))) >> 1] = f2bf(v);
      }
    }
  }
  __syncthreads();

  // ===== L1a-partial: G (g-part, W1a k=128..383) -> acc1a (registers) =====
  f32x4 acc1a[2][2];  // [nt][mt]
  #pragma unroll
  for (int nt = 0; nt < 2; ++nt)
    #pragma unroll
    for (int mt = 0; mt < 2; ++mt) acc1a[nt][mt] = z4;
  #pragma unroll
  for (int kc = 0; kc < 8; ++kc) {
    bf16x8 afr[2];
    #pragma unroll
    for (int mt = 0; mt < 2; ++mt) {
      int row = mt * 16 + ln;
      afr[mt] = *(const bf16x8*)&G[(row * 512 + (((kc * 32 + kcol) << 1) ^ ((row & 7) << 4))) >> 1];
    }
    #pragma unroll
    for (int nt = 0; nt < 2; ++nt) {
      int n = w * 32 + nt * 16 + ln;  // 0..127
      bf16x8 bfr = *(const bf16x8*)(wt1a + ((size_t)(e1 * 128 + n) * 384 + 128 + kc * 32 + kcol));
      #pragma unroll
      for (int mt = 0; mt < 2; ++mt)
        acc1a[nt][mt] = __builtin_amdgcn_mfma_f32_16x16x32_bf16(afr[mt], bfr, acc1a[nt][mt], 0, 0, 0);
    }
  }

  // ===== L00: feat0 @ W00[e0] -> H1 (256), relu (no barrier needed before this) =====
  #pragma unroll
  for (int nt = 0; nt < 4; ++nt) {
    int n = w * 64 + nt * 16 + ln;
    f32x4 acc[2] = {z4, z4};
    #pragma unroll
    for (int kc = 0; kc < 2; ++kc) {
      bf16x8 bfr = *(const bf16x8*)(wt00 + ((size_t)(e0 * 256 + n) * 64 + kc * 32 + kcol));
      #pragma unroll
      for (int mt = 0; mt < 2; ++mt)
        acc[mt] = __builtin_amdgcn_mfma_f32_16x16x32_bf16(axf[0][mt][kc], bfr, acc[mt], 0, 0, 0);
    }
    float bias = b00[e0 * 256 + n];
    #pragma unroll
    for (int mt = 0; mt < 2; ++mt) {
      #pragma unroll
      for (int r = 0; r < 4; ++r) {
        int row = mt * 16 + lq * 4 + r;
        float v = fmaxf(acc[mt][r] + bias, 0.f);
        H1m[(row * 512 + ((n << 1) ^ ((row & 7) << 4))) >> 1] = f2bf(v);
      }
    }
  }
  __syncthreads();

  // ===== L01: H1 @ W01[e0] -> HO (128, aliases dead G), relu =====
  {
    f32x4 acc[2][2];  // [nt][mt]
    #pragma unroll
    for (int nt = 0; nt < 2; ++nt)
      #pragma unroll
      for (int mt = 0; mt < 2; ++mt) acc[nt][mt] = z4;
    #pragma unroll
    for (int kc = 0; kc < 8; ++kc) {
      bf16x8 afr[2];
      #pragma unroll
      for (int mt = 0; mt < 2; ++mt) {
        int row = mt * 16 + ln;
        afr[mt] = *(const bf16x8*)&H1m[(row * 512 + (((kc * 32 + kcol) << 1) ^ ((row & 7) << 4))) >> 1];
      }
      #pragma unroll
      for (int nt = 0; nt < 2; ++nt) {
        int n = w * 32 + nt * 16 + ln;
        bf16x8 bfr = *(const bf16x8*)(wt01 + ((size_t)(e0 * 128 + n) * 256 + kc * 32 + kcol));
        #pragma unroll
        for (int mt = 0; mt < 2; ++mt)
          acc[nt][mt] = __builtin_amdgcn_mfma_f32_16x16x32_bf16(afr[mt], bfr, acc[nt][mt], 0, 0, 0);
      }
    }
    __syncthreads();  // all G-reads (L1a-partial) and H1-reads done; HO may overwrite G
    #pragma unroll
    for (int nt = 0; nt < 2; ++nt) {
      int n = w * 32 + nt * 16 + ln;
      float bias = b01[e0 * 128 + n];
      #pragma unroll
      for (int mt = 0; mt < 2; ++mt) {
        #pragma unroll
        for (int r = 0; r < 4; ++r) {
          int row = mt * 16 + lq * 4 + r;
          float v = fmaxf(acc[nt][mt][r] + bias, 0.f);
          HO[(row * 256 + ((n << 1) ^ ((row & 7) << 4))) >> 1] = f2bf(v);
        }
      }
    }
  }
  __syncthreads();

  // ===== L1a-finish: HO (h-part, W1a k=0..127) -> acc1a; relu -> G2 =====
  #pragma unroll
  for (int kc = 0; kc < 4; ++kc) {
    bf16x8 afr[2];
    #pragma unroll
    for (int mt = 0; mt < 2; ++mt) {
      int row = mt * 16 + ln;
      afr[mt] = *(const bf16x8*)&HO[(row * 256 + (((kc * 32 + kcol) << 1) ^ ((row & 7) << 4))) >> 1];
    }
    #pragma unroll
    for (int nt = 0; nt < 2; ++nt) {
      int n = w * 32 + nt * 16 + ln;
      bf16x8 bfr = *(const bf16x8*)(wt1a + ((size_t)(e1 * 128 + n) * 384 + kc * 32 + kcol));
      #pragma unroll
      for (int mt = 0; mt < 2; ++mt)
        acc1a[nt][mt] = __builtin_amdgcn_mfma_f32_16x16x32_bf16(afr[mt], bfr, acc1a[nt][mt], 0, 0, 0);
    }
  }
  __syncthreads();  // HO reads done; G2 (aliasing G upper half) write is to a disjoint region anyway
  #pragma unroll
  for (int nt = 0; nt < 2; ++nt) {
    int n = w * 32 + nt * 16 + ln;
    float bias = b1a[e1 * 128 + n];
    #pragma unroll
    for (int mt = 0; mt < 2; ++mt) {
      #pragma unroll
      for (int r = 0; r < 4; ++r) {
        int row = mt * 16 + lq * 4 + r;
        float v = fmaxf(acc1a[nt][mt][r] + bias, 0.f);
        G2[(row * 256 + ((n << 1) ^ ((row & 7) << 4))) >> 1] = f2bf(v);
      }
    }
  }
  __syncthreads();

  // ===== L1o: G2 @ W1o[e1] -> out (32), no relu, fp32 scatter =====
  {
    int mt = w & 1;
    int n  = (w >> 1) * 16 + ln;  // 0..31
    f32x4 acc = z4;
    #pragma unroll
    for (int kc = 0; kc < 4; ++kc) {
      int row = mt * 16 + ln;
      bf16x8 afr = *(const bf16x8*)&G2[(row * 256 + (((kc * 32 + kcol) << 1) ^ ((row & 7) << 4))) >> 1];
      bf16x8 bfr = *(const bf16x8*)(wt1o + ((size_t)(e1 * 32 + n) * 128 + kc * 32 + kcol));
      acc = __builtin_amdgcn_mfma_f32_16x16x32_bf16(afr, bfr, acc, 0, 0, 0);
    }
    float bias = b1o[e1 * 32 + n];
    #pragma unroll
    for (int r = 0; r < 4; ++r) {
      int row = mt * 16 + lq * 4 + r;
      if (row < nr) {
        int rg = rl[row];
        out[(size_t)rg * 32 + n] = acc[r] + bias;
      }
    }
  }
}

extern "C" void kernel_launch(void* const* d_in, const int* in_sizes, int n_in,
                              void* d_out, int out_size, void* d_ws, size_t ws_size,
                              hipStream_t stream) {
  const float* inp = (const float*)d_in[0];
  const float* w00 = (const float*)d_in[1];
  const float* b00 = (const float*)d_in[2];
  const float* w01 = (const float*)d_in[3];
  const float* b01 = (const float*)d_in[4];
  const float* w1p = (const float*)d_in[5];
  const float* b1p = (const float*)d_in[6];
  const float* w1a = (const float*)d_in[7];
  const float* b1a = (const float*)d_in[8];
  const float* w1o = (const float*)d_in[9];
  const float* b1o = (const float*)d_in[10];
  char*  ws  = (char*)d_ws;
  float* out = (float*)d_out;

  k_prep<<<240, 256, 0, stream>>>(w00, w01, w1p, w1a, w1o, ws);
  k_route<<<NBLK, 256, 0, stream>>>(inp, (int*)(ws + WS_PAIR), (int*)(ws + WS_BH));
  k_scan<<<1, 64, 0, stream>>>((const int*)(ws + WS_BH), (int*)(ws + WS_CNT),
                               (int*)(ws + WS_BASE), (int*)(ws + WS_OFF),
                               (int*)(ws + WS_SCHED), (int*)(ws + WS_NSCHED));
  k_scatter<<<NBLK, 256, 0, stream>>>((const int*)(ws + WS_PAIR),
                                      (const int*)(ws + WS_OFF),
                                      (int*)(ws + WS_ROWLIST));
  k_fused<<<MAXSCHED, 256, 0, stream>>>(inp, b00, b01, b1p, b1a, b1o, ws, out);
}

// Round 3
// 63.176 us; speedup vs baseline: 1.9399x; 1.5817x over previous
//
#include <hip/hip_runtime.h>
#include <hip/hip_bf16.h>

#define BATCH     32768
#define TILE      32
#define NPAIR     64
#define NBLK      128          /* route blocks: BATCH/256 */
#define MAXSCHED  1088         /* 64 + BATCH/TILE */

typedef __bf16 bf16x8 __attribute__((ext_vector_type(8)));
typedef float  f32x4  __attribute__((ext_vector_type(4)));
static_assert(sizeof(bf16x8) == 16, "bf16x8 must be 16B");

// ---- workspace byte offsets ----
#define WS_BH       1024
#define WS_OFF      (WS_BH + NBLK*NPAIR*4)          /* 33792 */
#define WS_SCHED    (WS_OFF + NBLK*NPAIR*4)         /* 66560, int4 per tile */
#define WS_PAIR     (WS_SCHED + MAXSCHED*16)        /* 83968 */
#define WS_ROWLIST  (WS_PAIR + BATCH*4)
#define WS_WT00     (WS_ROWLIST + BATCH*4)
#define WS_WT01     (WS_WT00 + 131072*2)
#define WS_WT1P     (WS_WT01 + 262144*2)
#define WS_WT1A     (WS_WT1P + 131072*2)
#define WS_WT1O     (WS_WT1A + 393216*2)

__device__ __forceinline__ unsigned short f2bf(float x) {
  __bf16 h = (__bf16)x;
  return __builtin_bit_cast(unsigned short, h);
}

// Merged: blocks 0..239 transpose weights fp32->bf16 [m][o][i]; blocks 240..367 route.
__global__ __launch_bounds__(256) void k_combo(const float* __restrict__ w00,
                                               const float* __restrict__ w01,
                                               const float* __restrict__ w1p,
                                               const float* __restrict__ w1a,
                                               const float* __restrict__ w1o,
                                               const float* __restrict__ inp,
                                               char* __restrict__ ws) {
  __shared__ unsigned short lds[64 * 72];
  int bid = blockIdx.x;
  if (bid >= 240) {
    // ---- route: per-block histogram, NO global atomics ----
    int* h = (int*)lds;
    int rbid = bid - 240;
    int t = threadIdx.x;
    if (t < NPAIR) h[t] = 0;
    __syncthreads();
    int r = rbid * 256 + t;
    const float* q = inp + (size_t)r * 144 + 128;
    float4 u0 = *(const float4*)(q + 0);
    float4 u1 = *(const float4*)(q + 4);
    float4 v0 = *(const float4*)(q + 8);
    float4 v1 = *(const float4*)(q + 12);
    int a0 = 0;
    if (u0.y > 0.5f) a0 = 1; if (u0.z > 0.5f) a0 = 2; if (u0.w > 0.5f) a0 = 3;
    if (u1.x > 0.5f) a0 = 4; if (u1.y > 0.5f) a0 = 5; if (u1.z > 0.5f) a0 = 6; if (u1.w > 0.5f) a0 = 7;
    int a1 = 0;
    if (v0.y > 0.5f) a1 = 1; if (v0.z > 0.5f) a1 = 2; if (v0.w > 0.5f) a1 = 3;
    if (v1.x > 0.5f) a1 = 4; if (v1.y > 0.5f) a1 = 5; if (v1.z > 0.5f) a1 = 6; if (v1.w > 0.5f) a1 = 7;
    int p = a0 * 8 + a1;
    ((int*)(ws + WS_PAIR))[r] = p;
    atomicAdd(&h[p], 1);
    __syncthreads();
    if (t < NPAIR) ((int*)(ws + WS_BH))[rbid * NPAIR + t] = h[t];
    return;
  }
  // ---- weight transpose ----
  const float* src; unsigned short* dst; int I, O, lt;
  if (bid < 32)       { src = w00; dst = (unsigned short*)(ws + WS_WT00); I = 64;  O = 256; lt = bid; }
  else if (bid < 96)  { src = w01; dst = (unsigned short*)(ws + WS_WT01); I = 256; O = 128; lt = bid - 32; }
  else if (bid < 128) { src = w1p; dst = (unsigned short*)(ws + WS_WT1P); I = 64;  O = 256; lt = bid - 96; }
  else if (bid < 224) { src = w1a; dst = (unsigned short*)(ws + WS_WT1A); I = 384; O = 128; lt = bid - 128; }
  else                { src = w1o; dst = (unsigned short*)(ws + WS_WT1O); I = 128; O = 32;  lt = bid - 224; }
  int tI = I >> 6;
  int tO = (O + 63) >> 6;
  int m   = lt / (tI * tO);
  int rem = lt % (tI * tO);
  int ib = rem / tO, ob = rem % tO;
  int tx = threadIdx.x & 63, ty = threadIdx.x >> 6;
  const float* s = src + (size_t)m * I * O;
  #pragma unroll 4
  for (int s4 = 0; s4 < 16; ++s4) {
    int li = s4 * 4 + ty;
    int o  = ob * 64 + tx;
    float v = (o < O) ? s[(size_t)(ib * 64 + li) * O + o] : 0.f;
    lds[li * 72 + tx] = f2bf(v);
  }
  __syncthreads();
  unsigned short* d = dst + (size_t)m * O * I;
  #pragma unroll 4
  for (int s4 = 0; s4 < 16; ++s4) {
    int lo = s4 * 4 + ty;
    int o  = ob * 64 + lo;
    if (o < O) d[(size_t)o * I + ib * 64 + tx] = lds[tx * 72 + lo];
  }
}

// Scan: 1 block x 1024 threads. Chunked two-level scan; packs schedule as int4{p,rb,nr,0}.
__global__ __launch_bounds__(1024) void k_scan(const int* __restrict__ bh,
                                               int* __restrict__ off,
                                               int4* __restrict__ sched) {
  __shared__ int part[16][NPAIR];
  __shared__ int bs64[NPAIR];
  int tid = threadIdx.x;
  int p = tid & 63, c = tid >> 6;       // 16 chunks x 8 blocks
  int loc[8]; int s = 0;
  #pragma unroll
  for (int i = 0; i < 8; ++i) { loc[i] = s; s += bh[(c * 8 + i) * NPAIR + p]; }
  part[c][p] = s;
  for (int j = tid; j < MAXSCHED; j += 1024) sched[j] = make_int4(0, 0, 0, 0);
  __syncthreads();
  if (tid < 64) {
    int run = 0;
    #pragma unroll
    for (int c2 = 0; c2 < 16; ++c2) { int v = part[c2][p]; part[c2][p] = run; run += v; }
    int x = run;
    #pragma unroll
    for (int d = 1; d < 64; d <<= 1) { int y = __shfl_up(x, d); if (p >= d) x += y; }
    int bs = x - run;
    bs64[p] = bs;
    int nt = (run + TILE - 1) / TILE;
    int z = nt;
    #pragma unroll
    for (int d = 1; d < 64; d <<= 1) { int y = __shfl_up(z, d); if (p >= d) z += y; }
    int tb = z - nt;
    for (int t2 = 0; t2 < nt; ++t2)
      sched[tb + t2] = make_int4(p, bs + t2 * TILE, min(TILE, run - t2 * TILE), 0);
  }
  __syncthreads();
  int add = part[c][p] + bs64[p];
  #pragma unroll
  for (int i = 0; i < 8; ++i) off[(c * 8 + i) * NPAIR + p] = loc[i] + add;
}

// Scatter: LDS-local rank + precomputed global offset. NO global atomics.
__global__ __launch_bounds__(256) void k_scatter(const int* __restrict__ pairArr,
                                                 const int* __restrict__ off,
                                                 int* __restrict__ rowlist) {
  __shared__ int h[NPAIR];
  int t = threadIdx.x;
  if (t < NPAIR) h[t] = 0;
  __syncthreads();
  int r = blockIdx.x * 256 + t;
  int p = pairArr[r];
  int rank = atomicAdd(&h[p], 1);
  rowlist[off[blockIdx.x * NPAIR + p] + rank] = r;
}

// Fused 5-layer routed MLP. One block = 32 rows sharing (a0,a1); 4 waves; 48KB LDS,
// 3 barriers, explicit cross-barrier weight prefetch (T14).
// Order: L1p->G, L00->H1 | bar | L1a-partial(G), L01(H1)->HO | bar |
//        L1a-finish(HO)->G2 | bar | L1o(G2)->out.
// Swizzle: byte ^= (row&7)<<4 on all tiles.
__global__ __launch_bounds__(256, 3) void k_fused(
    const float* __restrict__ inp,
    const float* __restrict__ b00, const float* __restrict__ b01,
    const float* __restrict__ b1p, const float* __restrict__ b1a,
    const float* __restrict__ b1o,
    const char* __restrict__ ws, float* __restrict__ out)
{
  __shared__ char smem[49152];
  unsigned short* G   = (unsigned short*)smem;            // 32x256, stride 512B
  unsigned short* H1m = (unsigned short*)(smem + 16384);  // 32x256, stride 512B
  unsigned short* HO  = (unsigned short*)(smem + 32768);  // 32x128, stride 256B
  unsigned short* G2  = (unsigned short*)(smem + 40960);  // 32x128, stride 256B

  int4 se = ((const int4*)(ws + WS_SCHED))[blockIdx.x];
  int nr = se.z;
  if (nr <= 0) return;
  int p = se.x, rb = se.y;
  int e0 = p >> 3, e1 = p & 7;
  const int* rl = (const int*)(ws + WS_ROWLIST) + rb;

  const unsigned short* wt00 = (const unsigned short*)(ws + WS_WT00);
  const unsigned short* wt01 = (const unsigned short*)(ws + WS_WT01);
  const unsigned short* wt1p = (const unsigned short*)(ws + WS_WT1P);
  const unsigned short* wt1a = (const unsigned short*)(ws + WS_WT1A);
  const unsigned short* wt1o = (const unsigned short*)(ws + WS_WT1O);

  int lane = threadIdx.x & 63;
  int w    = threadIdx.x >> 6;   // wave 0..3
  int ln   = lane & 15;
  int lq   = lane >> 4;          // 0..3
  int kcol = lq * 8;

  int rowA[2];
  #pragma unroll
  for (int mt = 0; mt < 2; ++mt) {
    int rloc = mt * 16 + ln;
    rowA[mt] = (rloc < nr) ? rl[rloc] : -1;
  }

  // ---- top preloads: biases, L1p/L00 weights, input fragments ----
  float bias1p[4], bias00[4];
  #pragma unroll
  for (int nt = 0; nt < 4; ++nt) {
    int n = w * 64 + nt * 16 + ln;
    bias1p[nt] = b1p[e1 * 256 + n];
    bias00[nt] = b00[e0 * 256 + n];
  }
  float bias01[2], bias1a[2];
  #pragma unroll
  for (int nt = 0; nt < 2; ++nt) {
    int n = w * 32 + nt * 16 + ln;
    bias01[nt] = b01[e0 * 128 + n];
    bias1a[nt] = b1a[e1 * 128 + n];
  }
  float bias1o = b1o[e1 * 32 + (w >> 1) * 16 + ln];

  bf16x8 w1pf[4][2], w00f[4][2];
  #pragma unroll
  for (int nt = 0; nt < 4; ++nt) {
    int n = w * 64 + nt * 16 + ln;
    #pragma unroll
    for (int kc = 0; kc < 2; ++kc) {
      w1pf[nt][kc] = *(const bf16x8*)(wt1p + ((size_t)(e1 * 256 + n) * 64 + kc * 32 + kcol));
      w00f[nt][kc] = *(const bf16x8*)(wt00 + ((size_t)(e0 * 256 + n) * 64 + kc * 32 + kcol));
    }
  }

  bf16x8 axf[2][2][2];  // [half][mt][kc]
  #pragma unroll
  for (int mt = 0; mt < 2; ++mt) {
    #pragma unroll
    for (int half = 0; half < 2; ++half) {
      #pragma unroll
      for (int kc = 0; kc < 2; ++kc) {
        bf16x8 a;
        int rg = rowA[mt];
        if (rg >= 0) {
          const float* q = inp + (size_t)rg * 144 + half * 64 + kc * 32 + kcol;
          float4 u = *(const float4*)(q);
          float4 v = *(const float4*)(q + 4);
          a[0] = (__bf16)u.x; a[1] = (__bf16)u.y; a[2] = (__bf16)u.z; a[3] = (__bf16)u.w;
          a[4] = (__bf16)v.x; a[5] = (__bf16)v.y; a[6] = (__bf16)v.z; a[7] = (__bf16)v.w;
        } else {
          #pragma unroll
          for (int j = 0; j < 8; ++j) a[j] = (__bf16)0.f;
        }
        axf[half][mt][kc] = a;
      }
    }
  }

  const f32x4 z4 = {0.f, 0.f, 0.f, 0.f};

  // ===== L1p: feat1 @ W1p[e1] -> G (256), relu =====
  #pragma unroll
  for (int nt = 0; nt < 4; ++nt) {
    int n = w * 64 + nt * 16 + ln;
    f32x4 acc[2] = {z4, z4};
    #pragma unroll
    for (int kc = 0; kc < 2; ++kc)
      #pragma unroll
      for (int mt = 0; mt < 2; ++mt)
        acc[mt] = __builtin_amdgcn_mfma_f32_16x16x32_bf16(axf[1][mt][kc], w1pf[nt][kc], acc[mt], 0, 0, 0);
    #pragma unroll
    for (int mt = 0; mt < 2; ++mt)
      #pragma unroll
      for (int r = 0; r < 4; ++r) {
        int row = mt * 16 + lq * 4 + r;
        float v = fmaxf(acc[mt][r] + bias1p[nt], 0.f);
        G[(row * 512 + ((n << 1) ^ ((row & 7) << 4))) >> 1] = f2bf(v);
      }
  }

  // ===== L00: feat0 @ W00[e0] -> H1 (256), relu =====
  #pragma unroll
  for (int nt = 0; nt < 4; ++nt) {
    int n = w * 64 + nt * 16 + ln;
    f32x4 acc[2] = {z4, z4};
    #pragma unroll
    for (int kc = 0; kc < 2; ++kc)
      #pragma unroll
      for (int mt = 0; mt < 2; ++mt)
        acc[mt] = __builtin_amdgcn_mfma_f32_16x16x32_bf16(axf[0][mt][kc], w00f[nt][kc], acc[mt], 0, 0, 0);
    #pragma unroll
    for (int mt = 0; mt < 2; ++mt)
      #pragma unroll
      for (int r = 0; r < 4; ++r) {
        int row = mt * 16 + lq * 4 + r;
        float v = fmaxf(acc[mt][r] + bias00[nt], 0.f);
        H1m[(row * 512 + ((n << 1) ^ ((row & 7) << 4))) >> 1] = f2bf(v);
      }
  }

  // ---- prefetch across bar1: W1a g-part (all) + W01 first half ----
  bf16x8 wga[2][8];
  #pragma unroll
  for (int nt = 0; nt < 2; ++nt) {
    int n = w * 32 + nt * 16 + ln;
    #pragma unroll
    for (int kc = 0; kc < 8; ++kc)
      wga[nt][kc] = *(const bf16x8*)(wt1a + ((size_t)(e1 * 128 + n) * 384 + 128 + kc * 32 + kcol));
  }
  bf16x8 wc[2][8];
  #pragma unroll
  for (int nt = 0; nt < 2; ++nt) {
    int n = w * 32 + nt * 16 + ln;
    #pragma unroll
    for (int kc = 0; kc < 4; ++kc)
      wc[nt][kc] = *(const bf16x8*)(wt01 + ((size_t)(e0 * 128 + n) * 256 + kc * 32 + kcol));
  }
  __syncthreads();

  // ---- issue remaining W01 (overlaps L1a-partial) ----
  #pragma unroll
  for (int nt = 0; nt < 2; ++nt) {
    int n = w * 32 + nt * 16 + ln;
    #pragma unroll
    for (int kc = 4; kc < 8; ++kc)
      wc[nt][kc] = *(const bf16x8*)(wt01 + ((size_t)(e0 * 128 + n) * 256 + kc * 32 + kcol));
  }

  // ===== L1a-partial: G (g-part, k=128..383) -> acc1a =====
  f32x4 acc1a[2][2];
  #pragma unroll
  for (int nt = 0; nt < 2; ++nt)
    #pragma unroll
    for (int mt = 0; mt < 2; ++mt) acc1a[nt][mt] = z4;
  #pragma unroll
  for (int kc = 0; kc < 8; ++kc) {
    bf16x8 afr[2];
    #pragma unroll
    for (int mt = 0; mt < 2; ++mt) {
      int row = mt * 16 + ln;
      afr[mt] = *(const bf16x8*)&G[(row * 512 + (((kc * 32 + kcol) << 1) ^ ((row & 7) << 4))) >> 1];
    }
    #pragma unroll
    for (int nt = 0; nt < 2; ++nt)
      #pragma unroll
      for (int mt = 0; mt < 2; ++mt)
        acc1a[nt][mt] = __builtin_amdgcn_mfma_f32_16x16x32_bf16(afr[mt], wga[nt][kc], acc1a[nt][mt], 0, 0, 0);
  }

  // ===== L01: H1 @ W01[e0] -> HO (128), relu =====
  {
    f32x4 acc[2][2];
    #pragma unroll
    for (int nt = 0; nt < 2; ++nt)
      #pragma unroll
      for (int mt = 0; mt < 2; ++mt) acc[nt][mt] = z4;
    #pragma unroll
    for (int kc = 0; kc < 8; ++kc) {
      bf16x8 afr[2];
      #pragma unroll
      for (int mt = 0; mt < 2; ++mt) {
        int row = mt * 16 + ln;
        afr[mt] = *(const bf16x8*)&H1m[(row * 512 + (((kc * 32 + kcol) << 1) ^ ((row & 7) << 4))) >> 1];
      }
      #pragma unroll
      for (int nt = 0; nt < 2; ++nt)
        #pragma unroll
        for (int mt = 0; mt < 2; ++mt)
          acc[nt][mt] = __builtin_amdgcn_mfma_f32_16x16x32_bf16(afr[mt], wc[nt][kc], acc[nt][mt], 0, 0, 0);
    }
    #pragma unroll
    for (int nt = 0; nt < 2; ++nt) {
      int n = w * 32 + nt * 16 + ln;
      #pragma unroll
      for (int mt = 0; mt < 2; ++mt)
        #pragma unroll
        for (int r = 0; r < 4; ++r) {
          int row = mt * 16 + lq * 4 + r;
          float v = fmaxf(acc[nt][mt][r] + bias01[nt], 0.f);
          HO[(row * 256 + ((n << 1) ^ ((row & 7) << 4))) >> 1] = f2bf(v);
        }
    }
  }

  // ---- prefetch across bar2: W1a h-part + W1o ----
  bf16x8 wha[2][4];
  #pragma unroll
  for (int nt = 0; nt < 2; ++nt) {
    int n = w * 32 + nt * 16 + ln;
    #pragma unroll
    for (int kc = 0; kc < 4; ++kc)
      wha[nt][kc] = *(const bf16x8*)(wt1a + ((size_t)(e1 * 128 + n) * 384 + kc * 32 + kcol));
  }
  bf16x8 wo[4];
  {
    int n = (w >> 1) * 16 + ln;
    #pragma unroll
    for (int kc = 0; kc < 4; ++kc)
      wo[kc] = *(const bf16x8*)(wt1o + ((size_t)(e1 * 32 + n) * 128 + kc * 32 + kcol));
  }
  __syncthreads();

  // ===== L1a-finish: HO (h-part, k=0..127) -> acc1a; relu -> G2 =====
  #pragma unroll
  for (int kc = 0; kc < 4; ++kc) {
    bf16x8 afr[2];
    #pragma unroll
    for (int mt = 0; mt < 2; ++mt) {
      int row = mt * 16 + ln;
      afr[mt] = *(const bf16x8*)&HO[(row * 256 + (((kc * 32 + kcol) << 1) ^ ((row & 7) << 4))) >> 1];
    }
    #pragma unroll
    for (int nt = 0; nt < 2; ++nt)
      #pragma unroll
      for (int mt = 0; mt < 2; ++mt)
        acc1a[nt][mt] = __builtin_amdgcn_mfma_f32_16x16x32_bf16(afr[mt], wha[nt][kc], acc1a[nt][mt], 0, 0, 0);
  }
  #pragma unroll
  for (int nt = 0; nt < 2; ++nt) {
    int n = w * 32 + nt * 16 + ln;
    #pragma unroll
    for (int mt = 0; mt < 2; ++mt)
      #pragma unroll
      for (int r = 0; r < 4; ++r) {
        int row = mt * 16 + lq * 4 + r;
        float v = fmaxf(acc1a[nt][mt][r] + bias1a[nt], 0.f);
        G2[(row * 256 + ((n << 1) ^ ((row & 7) << 4))) >> 1] = f2bf(v);
      }
  }
  __syncthreads();

  // ===== L1o: G2 @ W1o[e1] -> out (32), no relu, fp32 scatter =====
  {
    int mt = w & 1;
    int n  = (w >> 1) * 16 + ln;
    f32x4 acc = z4;
    #pragma unroll
    for (int kc = 0; kc < 4; ++kc) {
      int row = mt * 16 + ln;
      bf16x8 afr = *(const bf16x8*)&G2[(row * 256 + (((kc * 32 + kcol) << 1) ^ ((row & 7) << 4))) >> 1];
      acc = __builtin_amdgcn_mfma_f32_16x16x32_bf16(afr, wo[kc], acc, 0, 0, 0);
    }
    #pragma unroll
    for (int r = 0; r < 4; ++r) {
      int row = mt * 16 + lq * 4 + r;
      if (row < nr) {
        int rg = rl[row];
        out[(size_t)rg * 32 + n] = acc[r] + bias1o;
      }
    }
  }
}

extern "C" void kernel_launch(void* const* d_in, const int* in_sizes, int n_in,
                              void* d_out, int out_size, void* d_ws, size_t ws_size,
                              hipStream_t stream) {
  const float* inp = (const float*)d_in[0];
  const float* w00 = (const float*)d_in[1];
  const float* b00 = (const float*)d_in[2];
  const float* w01 = (const float*)d_in[3];
  const float* b01 = (const float*)d_in[4];
  const float* w1p = (const float*)d_in[5];
  const float* b1p = (const float*)d_in[6];
  const float* w1a = (const float*)d_in[7];
  const float* b1a = (const float*)d_in[8];
  const float* w1o = (const float*)d_in[9];
  const float* b1o = (const float*)d_in[10];
  char*  ws  = (char*)d_ws;
  float* out = (float*)d_out;

  k_combo<<<368, 256, 0, stream>>>(w00, w01, w1p, w1a, w1o, inp, ws);
  k_scan<<<1, 1024, 0, stream>>>((const int*)(ws + WS_BH), (int*)(ws + WS_OFF),
                                 (int4*)(ws + WS_SCHED));
  k_scatter<<<NBLK, 256, 0, stream>>>((const int*)(ws + WS_PAIR),
                                      (const int*)(ws + WS_OFF),
                                      (int*)(ws + WS_ROWLIST));
  k_fused<<<MAXSCHED, 256, 0, stream>>>(inp, b00, b01, b1p, b1a, b1o, ws, out);
}